// Round 4
// baseline (10233.907 us; speedup 1.0000x reference)
//
#include <hip/hip_runtime.h>
#include <math.h>

#define DEVI static __device__ __forceinline__

DEVI float gelu_f(float x) { return 0.5f * x * (1.0f + erff(x * 0.70710678118654752440f)); }

// ---------------------------------------------------------------------------
// Direct 3x3 conv, pad=1. 256 threads = 256 spatial sites, 4 output channels
// per block (fp32 weights staged in LDS, broadcast reads). fp32 in/out.
// ---------------------------------------------------------------------------
__global__ __launch_bounds__(256)
void conv3x3_k(const float* __restrict__ in, const float* __restrict__ w,
               const float* __restrict__ bias, float* __restrict__ out,
               int Cin, int Cout, int Hin, int Win, int Hout, int Wout, int stride)
{
    __shared__ __align__(16) float wlds[4 * 9 * 256];  // [ci*9+k][4]
    int b = blockIdx.z;
    int co0 = blockIdx.y * 4;
    int tid = threadIdx.x;
    int nw = 4 * Cin * 9;
    for (int i = tid; i < nw; i += 256) {
        int j = i & 3;
        int rest = i >> 2;            // ci*9 + k
        int ci = rest / 9, kk = rest % 9;
        wlds[i] = w[((size_t)(co0 + j) * Cin + ci) * 9 + kk];
    }
    __syncthreads();
    int HWo = Hout * Wout;
    int s = blockIdx.x * 256 + tid;
    if (s >= HWo) return;
    int ho = s / Wout, wo = s % Wout;
    float acc0 = bias[co0], acc1 = bias[co0 + 1];
    float acc2 = bias[co0 + 2], acc3 = bias[co0 + 3];
    const float* inb = in + (size_t)b * Cin * Hin * Win;
    size_t HWi = (size_t)Hin * Win;
    for (int kh = 0; kh < 3; kh++) {
        int hi = ho * stride - 1 + kh;
        if (hi < 0 || hi >= Hin) continue;
        for (int kw = 0; kw < 3; kw++) {
            int wi = wo * stride - 1 + kw;
            if (wi < 0 || wi >= Win) continue;
            const float* ip = inb + (size_t)hi * Win + wi;
            const float* wp = wlds + (kh * 3 + kw) * 4;
            for (int ci = 0; ci < Cin; ci++) {
                float xv = ip[(size_t)ci * HWi];
                float4 wv = *(const float4*)(wp + (size_t)ci * 36);
                acc0 += xv * wv.x; acc1 += xv * wv.y;
                acc2 += xv * wv.z; acc3 += xv * wv.w;
            }
        }
    }
    size_t ob = ((size_t)b * Cout + co0) * HWo + s;
    out[ob] = acc0; out[ob + HWo] = acc1;
    out[ob + 2 * (size_t)HWo] = acc2; out[ob + 3 * (size_t)HWo] = acc3;
}

__global__ __launch_bounds__(128)
void zero_k(float* __restrict__ p) { p[threadIdx.x] = 0.f; }

// ---------------------------------------------------------------------------
// GroupNorm (fp32), two-phase with atomics into stats
// ---------------------------------------------------------------------------
__global__ __launch_bounds__(256)
void gn_stats_k(const float* __restrict__ x, float* __restrict__ stats,
                int C, int HW, int cpg, int S)
{
    int srt = blockIdx.x, g = blockIdx.y, b = blockIdx.z;
    long len = (long)cpg * HW;
    long chunk = (len + S - 1) / S;
    long lo = (long)srt * chunk;
    long hi = lo + chunk; if (hi > len) hi = len;
    const float* xp = x + ((size_t)b * C + (size_t)g * cpg) * HW;
    float s1 = 0.f, s2 = 0.f;
    for (long i = lo + threadIdx.x; i < hi; i += 256) {
        float v = xp[i];
        s1 += v; s2 += v * v;
    }
    __shared__ float r1[256], r2[256];
    r1[threadIdx.x] = s1; r2[threadIdx.x] = s2;
    __syncthreads();
    for (int t = 128; t > 0; t >>= 1) {
        if (threadIdx.x < t) { r1[threadIdx.x] += r1[threadIdx.x + t]; r2[threadIdx.x] += r2[threadIdx.x + t]; }
        __syncthreads();
    }
    if (threadIdx.x == 0) {
        atomicAdd(&stats[(b * 32 + g) * 2], r1[0]);
        atomicAdd(&stats[(b * 32 + g) * 2 + 1], r2[0]);
    }
}

__global__ __launch_bounds__(256)
void gn_apply_k(float* __restrict__ x, const float* __restrict__ stats,
                const float* __restrict__ gma, const float* __restrict__ bta,
                int C, int HW, int cpg, int do_gelu, int total)
{
    int idx = blockIdx.x * 256 + threadIdx.x;
    if (idx >= total) return;
    int c = (idx / HW) % C;
    int b = idx / (HW * C);
    int g = c / cpg;
    float cnt = (float)cpg * (float)HW;
    float s1 = stats[(b * 32 + g) * 2], s2 = stats[(b * 32 + g) * 2 + 1];
    float m = s1 / cnt;
    float var = s2 / cnt - m * m;
    float inv = rsqrtf(var + 1e-5f);
    float v = (x[idx] - m) * inv * gma[c] + bta[c];
    if (do_gelu) v = gelu_f(v);
    x[idx] = v;
}

// ---------------------------------------------------------------------------
// Add DETR sine position embedding: fp32 -> fp32 X
// ---------------------------------------------------------------------------
__global__ __launch_bounds__(256)
void posadd_k(const float* __restrict__ xin, float* __restrict__ xout)
{
    int idx = blockIdx.x * 256 + threadIdx.x;
    if (idx >= 2 * 256 * 2500) return;
    int t = idx % 2500;
    int ch = (idx / 2500) % 256;
    int yy = t / 50, xx = t % 50;
    int cc = ch & 127;
    float v = (ch < 128) ? (float)(yy + 1) : (float)(xx + 1);
    v = v * (6.283185307179586f / 50.0f);
    float e = (float)(2 * (cc >> 1)) / 128.0f;
    float d = exp2f(e * 13.287712379549449f);  // log2(10000)
    float a = v / d;
    float p = (cc & 1) ? cosf(a) : sinf(a);
    xout[idx] = xin[idx] + p;
}

// ---------------------------------------------------------------------------
// Pointwise GEMM: C[b] = act((A * B[b] + bias) * gamma + beta) (+res)
// All fp32. 64x64 tile, 16x16 threads x 4x4 microtile, K-chunk 16.
// ---------------------------------------------------------------------------
__global__ __launch_bounds__(256)
void gemm_k(const float* __restrict__ A, const float* __restrict__ Bm,
            float* __restrict__ Cm,
            const float* __restrict__ bias, const float* __restrict__ gma,
            const float* __restrict__ bta, const float* __restrict__ res,
            int M, int N, int K, int do_gelu)
{
    __shared__ __align__(16) float As[16][68];
    __shared__ __align__(16) float Bs[16][68];
    int b = blockIdx.z;
    const float* Bp = Bm + (size_t)b * K * N;
    float* Cp = Cm + (size_t)b * M * N;
    const float* Rp = res ? res + (size_t)b * M * N : nullptr;
    int n0 = blockIdx.x * 64, m0 = blockIdx.y * 64;
    int tid = threadIdx.x;
    int tx = tid % 16, ty = tid / 16;
    int la_k = tid % 16, la_m = tid / 16;
    int lb_n = tid % 64, lb_k = tid / 64;
    float acc[4][4] = {};
    for (int k0 = 0; k0 < K; k0 += 16) {
#pragma unroll
        for (int r = 0; r < 4; r++) {
            int m = la_m + r * 16;
            As[la_k][m] = A[(size_t)(m0 + m) * K + k0 + la_k];
        }
#pragma unroll
        for (int r = 0; r < 4; r++) {
            int kk = lb_k + r * 4;
            int n = n0 + lb_n;
            Bs[kk][lb_n] = (n < N) ? Bp[(size_t)(k0 + kk) * N + n] : 0.f;
        }
        __syncthreads();
#pragma unroll
        for (int kk = 0; kk < 16; kk++) {
            float4 av = *(const float4*)&As[kk][ty * 4];
            float4 bv = *(const float4*)&Bs[kk][tx * 4];
            acc[0][0] += av.x * bv.x; acc[0][1] += av.x * bv.y; acc[0][2] += av.x * bv.z; acc[0][3] += av.x * bv.w;
            acc[1][0] += av.y * bv.x; acc[1][1] += av.y * bv.y; acc[1][2] += av.y * bv.z; acc[1][3] += av.y * bv.w;
            acc[2][0] += av.z * bv.x; acc[2][1] += av.z * bv.y; acc[2][2] += av.z * bv.z; acc[2][3] += av.z * bv.w;
            acc[3][0] += av.w * bv.x; acc[3][1] += av.w * bv.y; acc[3][2] += av.w * bv.z; acc[3][3] += av.w * bv.w;
        }
        __syncthreads();
    }
#pragma unroll
    for (int i2 = 0; i2 < 4; i2++) {
        int m = m0 + ty * 4 + i2;
        float bs = bias ? bias[m] : 0.f;
        float gm = gma[m], bt = bta[m];
#pragma unroll
        for (int j2 = 0; j2 < 4; j2++) {
            int n = n0 + tx * 4 + j2;
            if (n < N) {
                float v = (acc[i2][j2] + bs) * gm + bt;
                if (do_gelu) v = gelu_f(v);
                if (Rp) v += Rp[(size_t)m * N + n];
                Cp[(size_t)m * N + n] = v;
            }
        }
    }
}

// ---------------------------------------------------------------------------
// Per-token: transpose HF [2,256,2500] -> HT [5000,256] (token-major),
// R[t] = rsqrt(sum x^2 + 1e-12), SQ[t] = sum (x*R)^2 = s*R^2.
// ---------------------------------------------------------------------------
__global__ __launch_bounds__(256)
void tok_k(const float* __restrict__ Hf, float* __restrict__ HT,
           float* __restrict__ R, float* __restrict__ SQ)
{
    int t = blockIdx.x * 256 + threadIdx.x;
    if (t >= 5000) return;
    int b = t / 2500, tt = t % 2500;
    const float* p = Hf + (size_t)b * 256 * 2500 + tt;
    float* ht = HT + (size_t)t * 256;
    float s = 0.f;
    for (int c = 0; c < 256; c++) {
        float v = p[(size_t)c * 2500];
        ht[c] = v;
        s += v * v;
    }
    float r = rsqrtf(s + 1e-12f);
    R[t] = r;
    SQ[t] = s * r * r;
}

// ---------------------------------------------------------------------------
// Pairwise neg sq distance for a row-chunk of one batch, normalizing on the
// fly: NEGc[i-r0][j] = 2*dot(xn_i,xn_j) - sq_i - sq_j, xn = HT*R.
// ---------------------------------------------------------------------------
__global__ __launch_bounds__(256)
void dist_k(const float* __restrict__ HT, const float* __restrict__ R,
            const float* __restrict__ SQ, float* __restrict__ NEGc,
            int b, int r0, int rows)
{
    __shared__ __align__(16) float As[16][68];
    __shared__ __align__(16) float Bs[16][68];
    const float* Xp = HT + (size_t)b * 2500 * 256;
    const float* Rp = R + (size_t)b * 2500;
    const float* Sp = SQ + (size_t)b * 2500;
    int n0 = blockIdx.x * 64, m0 = blockIdx.y * 64;  // m0 chunk-local
    int tid = threadIdx.x;
    int tx = tid % 16, ty = tid / 16;
    int lk = tid % 16, lr = tid / 16;
    float acc[4][4] = {};
    for (int k0 = 0; k0 < 256; k0 += 16) {
#pragma unroll
        for (int r = 0; r < 4; r++) {
            int m = lr + r * 16;
            int gi = r0 + m0 + m;
            As[lk][m] = (gi < 2500) ? Xp[(size_t)gi * 256 + k0 + lk] * Rp[gi] : 0.f;
            int gj = n0 + m;
            Bs[lk][m] = (gj < 2500) ? Xp[(size_t)gj * 256 + k0 + lk] * Rp[gj] : 0.f;
        }
        __syncthreads();
#pragma unroll
        for (int kk = 0; kk < 16; kk++) {
            float4 av = *(const float4*)&As[kk][ty * 4];
            float4 bv = *(const float4*)&Bs[kk][tx * 4];
            acc[0][0] += av.x * bv.x; acc[0][1] += av.x * bv.y; acc[0][2] += av.x * bv.z; acc[0][3] += av.x * bv.w;
            acc[1][0] += av.y * bv.x; acc[1][1] += av.y * bv.y; acc[1][2] += av.y * bv.z; acc[1][3] += av.y * bv.w;
            acc[2][0] += av.z * bv.x; acc[2][1] += av.z * bv.y; acc[2][2] += av.z * bv.z; acc[2][3] += av.z * bv.w;
            acc[3][0] += av.w * bv.x; acc[3][1] += av.w * bv.y; acc[3][2] += av.w * bv.z; acc[3][3] += av.w * bv.w;
        }
        __syncthreads();
    }
#pragma unroll
    for (int i2 = 0; i2 < 4; i2++) {
        int ml = m0 + ty * 4 + i2;          // chunk-local row
        int gi = r0 + ml;                    // global row
        if (ml >= rows || gi >= 2500) continue;
        float si = Sp[gi];
#pragma unroll
        for (int j2 = 0; j2 < 4; j2++) {
            int j = n0 + tx * 4 + j2;
            if (j >= 2500) continue;
            NEGc[(size_t)ml * 2500 + j] = 2.f * acc[i2][j2] - si - Sp[j];
        }
    }
}

// ---------------------------------------------------------------------------
// top-(k*dil) per row (descending, stable by index), keep every dil-th index.
// sel clamped so corrupt data can never fault downstream.
// ---------------------------------------------------------------------------
__global__ __launch_bounds__(256)
void topk_k(const float* __restrict__ NEGc, int* __restrict__ IDX,
            int obase, int kd, int dil, int kout)
{
    __shared__ float vals[2500];
    __shared__ float rv[256];
    __shared__ int ri[256];
    int i = blockIdx.x;
    const float* row = NEGc + (size_t)i * 2500;
    int tid = threadIdx.x;
    for (int j = tid; j < 2500; j += 256) vals[j] = row[j];
    __syncthreads();
    for (int t = 0; t < kd; t++) {
        float bv = -INFINITY;
        int bi = 0x7fffffff;
        for (int j = tid; j < 2500; j += 256) {
            float v = vals[j];
            if (v > bv) { bv = v; bi = j; }
        }
        rv[tid] = bv; ri[tid] = bi;
        __syncthreads();
        for (int s2 = 128; s2 > 0; s2 >>= 1) {
            if (tid < s2) {
                float ov = rv[tid + s2]; int oi = ri[tid + s2];
                if (ov > rv[tid] || (ov == rv[tid] && oi < ri[tid])) { rv[tid] = ov; ri[tid] = oi; }
            }
            __syncthreads();
        }
        int sel = ri[0];
        if ((unsigned)sel >= 2500u) sel = 0;   // fault-proof (NaN/garbage rows)
        if (tid == 0) {
            if (t % dil == 0) IDX[(size_t)(obase + i) * kout + t / dil] = sel;
            vals[sel] = -INFINITY;
        }
        __syncthreads();
    }
}

// ---------------------------------------------------------------------------
// Gather neighbors, diff = max_k (x_j - x_i), interleaved concat -> fp32 F
// F[b][2q][t] = x_i[q]; F[b][2q+1][t] = diff[q]
// ---------------------------------------------------------------------------
__global__ __launch_bounds__(256)
void gather_k(const float* __restrict__ HT, const int* __restrict__ IDX,
              float* __restrict__ F, int k)
{
    int t = blockIdx.x;
    int b = blockIdx.y;
    int q = threadIdx.x;  // 256 channels
    __shared__ int idx[18];
    if (q < k) {
        int ii = IDX[((size_t)b * 2500 + t) * k + q];
        if ((unsigned)ii >= 2500u) ii = 0;     // fault-proof
        idx[q] = ii;
    }
    __syncthreads();
    const float* base = HT + (size_t)b * 2500 * 256;
    float center = base[(size_t)t * 256 + q];
    float mx = -INFINITY;
    for (int kk = 0; kk < k; kk++) {
        float v = base[(size_t)idx[kk] * 256 + q];
        mx = fmaxf(mx, v - center);
    }
    float* Fp = F + (size_t)b * 512 * 2500;
    Fp[(size_t)(2 * q) * 2500 + t] = center;
    Fp[(size_t)(2 * q + 1) * 2500 + t] = mx;
}

__global__ __launch_bounds__(256)
void out_k(const float* __restrict__ X, float* __restrict__ out)
{
    int idx = blockIdx.x * 256 + threadIdx.x;
    if (idx >= 1280000) return;
    out[idx] = X[idx];
}

// ---------------------------------------------------------------------------
extern "C" void kernel_launch(void* const* d_in, const int* in_sizes, int n_in,
                              void* d_out, int out_size, void* d_ws, size_t ws_size,
                              hipStream_t stream)
{
    (void)in_sizes; (void)n_in; (void)out_size; (void)ws_size;
    const float* x_in = (const float*)d_in[0];
    const float *swp[5], *sbp[5], *sgp[5], *sbep[5];
    for (int i = 0; i < 5; i++) {
        swp[i] = (const float*)d_in[1 + 4 * i];
        sbp[i] = (const float*)d_in[2 + 4 * i];
        sgp[i] = (const float*)d_in[3 + 4 * i];
        sbep[i] = (const float*)d_in[4 + 4 * i];
    }
    const float* fc1_w = (const float*)d_in[21];
    const float* fc1_b = (const float*)d_in[22];
    const float* fc1_g = (const float*)d_in[23];
    const float* fc1_be = (const float*)d_in[24];
    const float* mr_w = (const float*)d_in[25];
    const float* mr_g = (const float*)d_in[26];
    const float* mr_be = (const float*)d_in[27];
    const float* fc2_w = (const float*)d_in[28];
    const float* fc2_b = (const float*)d_in[29];
    const float* fc2_g = (const float*)d_in[30];
    const float* fc2_be = (const float*)d_in[31];
    const float* ffn1_w = (const float*)d_in[32];
    const float* ffn1_b = (const float*)d_in[33];
    const float* ffn1_g = (const float*)d_in[34];
    const float* ffn1_be = (const float*)d_in[35];
    const float* ffn2_w = (const float*)d_in[36];
    const float* ffn2_b = (const float*)d_in[37];
    const float* ffn2_g = (const float*)d_in[38];
    const float* ffn2_be = (const float*)d_in[39];

    float* ws = (float*)d_ws;
    // ---- workspace (fp32 everywhere), total ~72.1 MiB, lifetime-aliased ----
    // A [0 .. 10.24M):    stem ping | HF (1.28M) then NEGc (2048x2500 = 5.12M)
    // B [10.24M..15.36M): stem pong | F (2.56M) + G (2.56M); HF2 aliases F
    // C [15.36M..16.64M): X
    // D [16.64M..17.92M): HT
    // tail: SQ(5000) R(5000) STATS(128) IDX(90000 ints)
    const size_t OA = 0, OB = 10240000, OC = 15360000, OD = 16640000;
    const size_t OSQ = 17920000, OR = 17925000, OST = 17930000, OIDX = 17930128;

    float* ping = ws + OA;
    float* pong = ws + OB;
    float* HF   = ws + OA;
    float* NEGc = ws + OA;
    float* F    = ws + OB;              // 2.56M
    float* G    = ws + OB + 2560000;    // 2.56M
    float* HF2  = ws + OB;              // 2.56M (aliases F, dead by then)
    float* X    = ws + OC;
    float* HT   = ws + OD;
    float* SQ   = ws + OSQ;
    float* R    = ws + OR;
    float* STATS = ws + OST;
    int* IDX = (int*)(ws + OIDX);

    // ---------------- stem ----------------
    int Ci[5] = {3, 32, 64, 128, 256}, Co[5] = {32, 64, 128, 256, 256};
    int Hi[5] = {800, 400, 200, 100, 50}, Ho[5] = {400, 200, 100, 50, 50};
    int St[5] = {2, 2, 2, 2, 1};
    int Ssub[5] = {8, 8, 4, 2, 2};
    float* cur = nullptr;
    for (int l = 0; l < 5; l++) {
        float* outb = (l % 2 == 0) ? ping : pong;
        int HWo = Ho[l] * Ho[l];
        dim3 g((HWo + 255) / 256, Co[l] / 4, 2);
        conv3x3_k<<<g, 256, 0, stream>>>((l == 0) ? x_in : cur, swp[l], sbp[l], outb,
                                         Ci[l], Co[l], Hi[l], Hi[l], Ho[l], Ho[l], St[l]);
        zero_k<<<1, 128, 0, stream>>>(STATS);
        int cpg = Co[l] / 32;
        gn_stats_k<<<dim3(Ssub[l], 32, 2), 256, 0, stream>>>(outb, STATS, Co[l], HWo, cpg, Ssub[l]);
        int total = 2 * Co[l] * HWo;
        gn_apply_k<<<(total + 255) / 256, 256, 0, stream>>>(outb, STATS, sgp[l], sbep[l],
                                                            Co[l], HWo, cpg, (l < 4) ? 1 : 0, total);
        cur = outb;
    }
    posadd_k<<<(1280000 + 255) / 256, 256, 0, stream>>>(cur, X);

    // ---------------- 12 Grapher + FFN blocks ----------------
    const int KS[12] = {9, 9, 10, 11, 12, 13, 13, 14, 15, 16, 17, 18};
    const int DILS[12] = {1, 1, 1, 1, 2, 2, 2, 2, 3, 3, 3, 3};
    const int D = 256, N = 2500;
    const int CH = 2048;  // NEG row-chunk (2048*2500 = 5.12M floats fits region A)

    for (int i = 0; i < 12; i++) {
        // fc1: HF = (W X + b)*g + be  (HF overwrites dead stem-ping region)
        gemm_k<<<dim3(40, 4, 2), 256, 0, stream>>>(
            fc1_w + (size_t)i * D * D, X, HF,
            fc1_b + i * D, fc1_g + i * D, fc1_be + i * D, nullptr, D, N, D, 0);
        // transpose + norms (HF -> HT, R, SQ; HF dead afterwards)
        tok_k<<<20, 256, 0, stream>>>(HF, HT, R, SQ);
        // pairwise distances + top-k, chunked over rows per batch
        for (int b = 0; b < 2; b++) {
            for (int r0 = 0; r0 < N; r0 += CH) {
                int rows = (N - r0 < CH) ? (N - r0) : CH;
                dist_k<<<dim3(40, (rows + 63) / 64, 1), 256, 0, stream>>>(HT, R, SQ, NEGc, b, r0, rows);
                topk_k<<<rows, 256, 0, stream>>>(NEGc, IDX, b * N + r0,
                                                 KS[i] * DILS[i], DILS[i], KS[i]);
            }
        }
        // gather + max-diff + interleaved concat -> F
        gather_k<<<dim3(2500, 2), 256, 0, stream>>>(HT, IDX, F, KS[i]);
        // mr: G = gelu((W F)*g + be), M=512, K=512
        gemm_k<<<dim3(40, 8, 2), 256, 0, stream>>>(
            mr_w + (size_t)i * 512 * 512, F, G,
            nullptr, mr_g + i * 512, mr_be + i * 512, nullptr, 512, N, 512, 1);
        // fc2: X = (W G + b)*g + be + X
        gemm_k<<<dim3(40, 4, 2), 256, 0, stream>>>(
            fc2_w + (size_t)i * D * 512, G, X,
            fc2_b + i * D, fc2_g + i * D, fc2_be + i * D, X, D, N, 512, 0);
        // ffn1: HF2 = gelu((W X + b)*g + be), M=1024 (HF2 aliases dead F)
        gemm_k<<<dim3(40, 16, 2), 256, 0, stream>>>(
            ffn1_w + (size_t)i * 1024 * D, X, HF2,
            ffn1_b + i * 1024, ffn1_g + i * 1024, ffn1_be + i * 1024, nullptr, 1024, N, D, 1);
        // ffn2: X = (W HF2 + b)*g + be + X
        gemm_k<<<dim3(40, 4, 2), 256, 0, stream>>>(
            ffn2_w + (size_t)i * D * 1024, HF2, X,
            ffn2_b + i * D, ffn2_g + i * D, ffn2_be + i * D, X, D, N, 1024, 0);
    }

    out_k<<<(1280000 + 255) / 256, 256, 0, stream>>>(X, (float*)d_out);
}

// Round 5
// 8810.222 us; speedup vs baseline: 1.1616x; 1.1616x over previous
//
#include <hip/hip_runtime.h>
#include <math.h>

#define DEVI static __device__ __forceinline__

DEVI float gelu_f(float x) { return 0.5f * x * (1.0f + erff(x * 0.70710678118654752440f)); }

// ---------------------------------------------------------------------------
// Direct 3x3 conv, pad=1. 256 threads = 256 spatial sites, 16 output channels
// per block (weights staged in 48KB LDS, broadcast reads). Accumulation order
// identical to the round-4 kernel: tap-outer (kh,kw), ci-inner.
// Cin<=64: stage all taps once. Cin>64: stage per-tap (9 stages, aligned
// barriers; threads never early-return - clamp + guarded store).
// ---------------------------------------------------------------------------
__global__ __launch_bounds__(256)
void conv3x3_k(const float* __restrict__ in, const float* __restrict__ w,
               const float* __restrict__ bias, float* __restrict__ out,
               int Cin, int Cout, int Hin, int Win, int Hout, int Wout, int stride)
{
    __shared__ __align__(16) float wlds[12288];  // 48 KB
    int b = blockIdx.z;
    int co0 = blockIdx.y * 16;
    int tid = threadIdx.x;
    int HWo = Hout * Wout;
    int s = blockIdx.x * 256 + tid;
    int sc = (s < HWo) ? s : (HWo - 1);
    int ho = sc / Wout, wo = sc % Wout;
    float acc[16];
#pragma unroll
    for (int j = 0; j < 16; j++) acc[j] = bias[co0 + j];
    const float* inb = in + (size_t)b * Cin * Hin * Win;
    size_t HWi = (size_t)Hin * Win;

#define CONV_FMA16(wq, xv)                                            \
    {                                                                 \
        float4 w0 = *(const float4*)(wq);                             \
        float4 w1 = *(const float4*)((wq) + 4);                       \
        float4 w2 = *(const float4*)((wq) + 8);                       \
        float4 w3 = *(const float4*)((wq) + 12);                      \
        acc[0] += (xv) * w0.x; acc[1] += (xv) * w0.y;                 \
        acc[2] += (xv) * w0.z; acc[3] += (xv) * w0.w;                 \
        acc[4] += (xv) * w1.x; acc[5] += (xv) * w1.y;                 \
        acc[6] += (xv) * w1.z; acc[7] += (xv) * w1.w;                 \
        acc[8] += (xv) * w2.x; acc[9] += (xv) * w2.y;                 \
        acc[10] += (xv) * w2.z; acc[11] += (xv) * w2.w;               \
        acc[12] += (xv) * w3.x; acc[13] += (xv) * w3.y;               \
        acc[14] += (xv) * w3.z; acc[15] += (xv) * w3.w;               \
    }

    if (Cin <= 64) {
        // stage all 9 taps: wlds[(tap*Cin + ci)*16 + j]
        int nw = 16 * Cin * 9;
        for (int i = tid; i < nw; i += 256) {
            int j = i & 15;
            int rest = i >> 4;           // tap*Cin + ci
            int ci = rest % Cin, tap = rest / Cin;
            wlds[i] = w[((size_t)(co0 + j) * Cin + ci) * 9 + tap];
        }
        __syncthreads();
        for (int kh = 0; kh < 3; kh++) {
            int hi = ho * stride - 1 + kh;
            bool okh = (hi >= 0 && hi < Hin);
            for (int kw = 0; kw < 3; kw++) {
                int wi = wo * stride - 1 + kw;
                if (!okh || wi < 0 || wi >= Win) continue;
                int tap = kh * 3 + kw;
                const float* ip = inb + (size_t)hi * Win + wi;
                const float* wp = wlds + (size_t)tap * Cin * 16;
                for (int ci = 0; ci < Cin; ci++) {
                    float xv = ip[(size_t)ci * HWi];
                    const float* wq = wp + ci * 16;
                    CONV_FMA16(wq, xv);
                }
            }
        }
    } else {
        // per-tap staging: wlds[ci*16 + j]; barriers aligned across block
        for (int tap = 0; tap < 9; tap++) {
            __syncthreads();
            int nw = 16 * Cin;
            for (int i = tid; i < nw; i += 256) {
                int j = i & 15;
                int ci = i >> 4;
                wlds[i] = w[((size_t)(co0 + j) * Cin + ci) * 9 + tap];
            }
            __syncthreads();
            int kh = tap / 3, kw = tap % 3;
            int hi = ho * stride - 1 + kh;
            int wi = wo * stride - 1 + kw;
            if (hi < 0 || hi >= Hin || wi < 0 || wi >= Win) continue;
            const float* ip = inb + (size_t)hi * Win + wi;
            for (int ci = 0; ci < Cin; ci++) {
                float xv = ip[(size_t)ci * HWi];
                const float* wq = wlds + ci * 16;
                CONV_FMA16(wq, xv);
            }
        }
    }
#undef CONV_FMA16

    if (s < HWo) {
        size_t ob = ((size_t)b * Cout + co0) * HWo + s;
#pragma unroll
        for (int j = 0; j < 16; j++) out[ob + (size_t)j * HWo] = acc[j];
    }
}

__global__ __launch_bounds__(128)
void zero_k(float* __restrict__ p) { p[threadIdx.x] = 0.f; }

// ---------------------------------------------------------------------------
// GroupNorm (fp32), two-phase with atomics into stats
// ---------------------------------------------------------------------------
__global__ __launch_bounds__(256)
void gn_stats_k(const float* __restrict__ x, float* __restrict__ stats,
                int C, int HW, int cpg, int S)
{
    int srt = blockIdx.x, g = blockIdx.y, b = blockIdx.z;
    long len = (long)cpg * HW;
    long chunk = (len + S - 1) / S;
    long lo = (long)srt * chunk;
    long hi = lo + chunk; if (hi > len) hi = len;
    const float* xp = x + ((size_t)b * C + (size_t)g * cpg) * HW;
    float s1 = 0.f, s2 = 0.f;
    for (long i = lo + threadIdx.x; i < hi; i += 256) {
        float v = xp[i];
        s1 += v; s2 += v * v;
    }
    __shared__ float r1[256], r2[256];
    r1[threadIdx.x] = s1; r2[threadIdx.x] = s2;
    __syncthreads();
    for (int t = 128; t > 0; t >>= 1) {
        if (threadIdx.x < t) { r1[threadIdx.x] += r1[threadIdx.x + t]; r2[threadIdx.x] += r2[threadIdx.x + t]; }
        __syncthreads();
    }
    if (threadIdx.x == 0) {
        atomicAdd(&stats[(b * 32 + g) * 2], r1[0]);
        atomicAdd(&stats[(b * 32 + g) * 2 + 1], r2[0]);
    }
}

__global__ __launch_bounds__(256)
void gn_apply_k(float* __restrict__ x, const float* __restrict__ stats,
                const float* __restrict__ gma, const float* __restrict__ bta,
                int C, int HW, int cpg, int do_gelu, int total)
{
    int idx = blockIdx.x * 256 + threadIdx.x;
    if (idx >= total) return;
    int c = (idx / HW) % C;
    int b = idx / (HW * C);
    int g = c / cpg;
    float cnt = (float)cpg * (float)HW;
    float s1 = stats[(b * 32 + g) * 2], s2 = stats[(b * 32 + g) * 2 + 1];
    float m = s1 / cnt;
    float var = s2 / cnt - m * m;
    float inv = rsqrtf(var + 1e-5f);
    float v = (x[idx] - m) * inv * gma[c] + bta[c];
    if (do_gelu) v = gelu_f(v);
    x[idx] = v;
}

// ---------------------------------------------------------------------------
// Add DETR sine position embedding: fp32 -> fp32 X
// ---------------------------------------------------------------------------
__global__ __launch_bounds__(256)
void posadd_k(const float* __restrict__ xin, float* __restrict__ xout)
{
    int idx = blockIdx.x * 256 + threadIdx.x;
    if (idx >= 2 * 256 * 2500) return;
    int t = idx % 2500;
    int ch = (idx / 2500) % 256;
    int yy = t / 50, xx = t % 50;
    int cc = ch & 127;
    float v = (ch < 128) ? (float)(yy + 1) : (float)(xx + 1);
    v = v * (6.283185307179586f / 50.0f);
    float e = (float)(2 * (cc >> 1)) / 128.0f;
    float d = exp2f(e * 13.287712379549449f);  // log2(10000)
    float a = v / d;
    float p = (cc & 1) ? cosf(a) : sinf(a);
    xout[idx] = xin[idx] + p;
}

// ---------------------------------------------------------------------------
// Pointwise GEMM: C[b] = act((A * B[b] + bias) * gamma + beta) (+res)
// All fp32. 64x64 tile, 16x16 threads x 4x4 microtile, K-chunk 16.
// (unchanged from round 4 - numerics preserved)
// ---------------------------------------------------------------------------
__global__ __launch_bounds__(256)
void gemm_k(const float* __restrict__ A, const float* __restrict__ Bm,
            float* __restrict__ Cm,
            const float* __restrict__ bias, const float* __restrict__ gma,
            const float* __restrict__ bta, const float* __restrict__ res,
            int M, int N, int K, int do_gelu)
{
    __shared__ __align__(16) float As[16][68];
    __shared__ __align__(16) float Bs[16][68];
    int b = blockIdx.z;
    const float* Bp = Bm + (size_t)b * K * N;
    float* Cp = Cm + (size_t)b * M * N;
    const float* Rp = res ? res + (size_t)b * M * N : nullptr;
    int n0 = blockIdx.x * 64, m0 = blockIdx.y * 64;
    int tid = threadIdx.x;
    int tx = tid % 16, ty = tid / 16;
    int la_k = tid % 16, la_m = tid / 16;
    int lb_n = tid % 64, lb_k = tid / 64;
    float acc[4][4] = {};
    for (int k0 = 0; k0 < K; k0 += 16) {
#pragma unroll
        for (int r = 0; r < 4; r++) {
            int m = la_m + r * 16;
            As[la_k][m] = A[(size_t)(m0 + m) * K + k0 + la_k];
        }
#pragma unroll
        for (int r = 0; r < 4; r++) {
            int kk = lb_k + r * 4;
            int n = n0 + lb_n;
            Bs[kk][lb_n] = (n < N) ? Bp[(size_t)(k0 + kk) * N + n] : 0.f;
        }
        __syncthreads();
#pragma unroll
        for (int kk = 0; kk < 16; kk++) {
            float4 av = *(const float4*)&As[kk][ty * 4];
            float4 bv = *(const float4*)&Bs[kk][tx * 4];
            acc[0][0] += av.x * bv.x; acc[0][1] += av.x * bv.y; acc[0][2] += av.x * bv.z; acc[0][3] += av.x * bv.w;
            acc[1][0] += av.y * bv.x; acc[1][1] += av.y * bv.y; acc[1][2] += av.y * bv.z; acc[1][3] += av.y * bv.w;
            acc[2][0] += av.z * bv.x; acc[2][1] += av.z * bv.y; acc[2][2] += av.z * bv.z; acc[2][3] += av.z * bv.w;
            acc[3][0] += av.w * bv.x; acc[3][1] += av.w * bv.y; acc[3][2] += av.w * bv.z; acc[3][3] += av.w * bv.w;
        }
        __syncthreads();
    }
#pragma unroll
    for (int i2 = 0; i2 < 4; i2++) {
        int m = m0 + ty * 4 + i2;
        float bs = bias ? bias[m] : 0.f;
        float gm = gma[m], bt = bta[m];
#pragma unroll
        for (int j2 = 0; j2 < 4; j2++) {
            int n = n0 + tx * 4 + j2;
            if (n < N) {
                float v = (acc[i2][j2] + bs) * gm + bt;
                if (do_gelu) v = gelu_f(v);
                if (Rp) v += Rp[(size_t)m * N + n];
                Cp[(size_t)m * N + n] = v;
            }
        }
    }
}

// ---------------------------------------------------------------------------
// Per-token: transpose HF [2,256,2500] -> HT [5000,256] (token-major),
// R[t] = rsqrt(sum x^2 + 1e-12), SQ[t] = sum (x*R)^2 = s*R^2.
// ---------------------------------------------------------------------------
__global__ __launch_bounds__(256)
void tok_k(const float* __restrict__ Hf, float* __restrict__ HT,
           float* __restrict__ R, float* __restrict__ SQ)
{
    int t = blockIdx.x * 256 + threadIdx.x;
    if (t >= 5000) return;
    int b = t / 2500, tt = t % 2500;
    const float* p = Hf + (size_t)b * 256 * 2500 + tt;
    float* ht = HT + (size_t)t * 256;
    float s = 0.f;
    for (int c = 0; c < 256; c++) {
        float v = p[(size_t)c * 2500];
        ht[c] = v;
        s += v * v;
    }
    float r = rsqrtf(s + 1e-12f);
    R[t] = r;
    SQ[t] = s * r * r;
}

// ---------------------------------------------------------------------------
// Pairwise neg sq distance for a row-chunk, both batches via blockIdx.z:
// NEGc[bz][i-r0][j] = 2*dot(xn_i,xn_j) - sq_i - sq_j, xn = HT*R.
// ---------------------------------------------------------------------------
__global__ __launch_bounds__(256)
void dist_k(const float* __restrict__ HT, const float* __restrict__ R,
            const float* __restrict__ SQ, float* __restrict__ NEGc,
            int r0, int rows)
{
    __shared__ __align__(16) float As[16][68];
    __shared__ __align__(16) float Bs[16][68];
    int b = blockIdx.z;
    const float* Xp = HT + (size_t)b * 2500 * 256;
    const float* Rp = R + (size_t)b * 2500;
    const float* Sp = SQ + (size_t)b * 2500;
    float* Np = NEGc + (size_t)b * rows * 2500;
    int n0 = blockIdx.x * 64, m0 = blockIdx.y * 64;  // m0 chunk-local
    int tid = threadIdx.x;
    int tx = tid % 16, ty = tid / 16;
    int lk = tid % 16, lr = tid / 16;
    float acc[4][4] = {};
    for (int k0 = 0; k0 < 256; k0 += 16) {
#pragma unroll
        for (int r = 0; r < 4; r++) {
            int m = lr + r * 16;
            int gi = r0 + m0 + m;
            As[lk][m] = (gi < 2500) ? Xp[(size_t)gi * 256 + k0 + lk] * Rp[gi] : 0.f;
            int gj = n0 + m;
            Bs[lk][m] = (gj < 2500) ? Xp[(size_t)gj * 256 + k0 + lk] * Rp[gj] : 0.f;
        }
        __syncthreads();
#pragma unroll
        for (int kk = 0; kk < 16; kk++) {
            float4 av = *(const float4*)&As[kk][ty * 4];
            float4 bv = *(const float4*)&Bs[kk][tx * 4];
            acc[0][0] += av.x * bv.x; acc[0][1] += av.x * bv.y; acc[0][2] += av.x * bv.z; acc[0][3] += av.x * bv.w;
            acc[1][0] += av.y * bv.x; acc[1][1] += av.y * bv.y; acc[1][2] += av.y * bv.z; acc[1][3] += av.y * bv.w;
            acc[2][0] += av.z * bv.x; acc[2][1] += av.z * bv.y; acc[2][2] += av.z * bv.z; acc[2][3] += av.z * bv.w;
            acc[3][0] += av.w * bv.x; acc[3][1] += av.w * bv.y; acc[3][2] += av.w * bv.z; acc[3][3] += av.w * bv.w;
        }
        __syncthreads();
    }
#pragma unroll
    for (int i2 = 0; i2 < 4; i2++) {
        int ml = m0 + ty * 4 + i2;          // chunk-local row
        int gi = r0 + ml;                    // global row
        if (ml >= rows || gi >= 2500) continue;
        float si = Sp[gi];
#pragma unroll
        for (int j2 = 0; j2 < 4; j2++) {
            int j = n0 + tx * 4 + j2;
            if (j >= 2500) continue;
            Np[(size_t)ml * 2500 + j] = 2.f * acc[i2][j2] - si - Sp[j];
        }
    }
}

// ---------------------------------------------------------------------------
// top-(k*dil) per row (descending, stable by index), keep every dil-th index.
// blockIdx.y = batch. sel clamped so corrupt data can never fault downstream.
// ---------------------------------------------------------------------------
__global__ __launch_bounds__(256)
void topk_k(const float* __restrict__ NEGc, int* __restrict__ IDX,
            int r0, int rows, int kd, int dil, int kout)
{
    __shared__ float vals[2500];
    __shared__ float rv[256];
    __shared__ int ri[256];
    int i = blockIdx.x;
    int b = blockIdx.y;
    const float* row = NEGc + ((size_t)b * rows + i) * 2500;
    int tid = threadIdx.x;
    for (int j = tid; j < 2500; j += 256) vals[j] = row[j];
    __syncthreads();
    for (int t = 0; t < kd; t++) {
        float bv = -INFINITY;
        int bi = 0x7fffffff;
        for (int j = tid; j < 2500; j += 256) {
            float v = vals[j];
            if (v > bv) { bv = v; bi = j; }
        }
        rv[tid] = bv; ri[tid] = bi;
        __syncthreads();
        for (int s2 = 128; s2 > 0; s2 >>= 1) {
            if (tid < s2) {
                float ov = rv[tid + s2]; int oi = ri[tid + s2];
                if (ov > rv[tid] || (ov == rv[tid] && oi < ri[tid])) { rv[tid] = ov; ri[tid] = oi; }
            }
            __syncthreads();
        }
        int sel = ri[0];
        if ((unsigned)sel >= 2500u) sel = 0;   // fault-proof (NaN/garbage rows)
        if (tid == 0) {
            if (t % dil == 0) IDX[(size_t)(b * 2500 + r0 + i) * kout + t / dil] = sel;
            vals[sel] = -INFINITY;
        }
        __syncthreads();
    }
}

// ---------------------------------------------------------------------------
// Gather neighbors, diff = max_k (x_j - x_i), interleaved concat -> fp32 F
// F[b][2q][t] = x_i[q]; F[b][2q+1][t] = diff[q]
// ---------------------------------------------------------------------------
__global__ __launch_bounds__(256)
void gather_k(const float* __restrict__ HT, const int* __restrict__ IDX,
              float* __restrict__ F, int k)
{
    int t = blockIdx.x;
    int b = blockIdx.y;
    int q = threadIdx.x;  // 256 channels
    __shared__ int idx[18];
    if (q < k) {
        int ii = IDX[((size_t)b * 2500 + t) * k + q];
        if ((unsigned)ii >= 2500u) ii = 0;     // fault-proof
        idx[q] = ii;
    }
    __syncthreads();
    const float* base = HT + (size_t)b * 2500 * 256;
    float center = base[(size_t)t * 256 + q];
    float mx = -INFINITY;
    for (int kk = 0; kk < k; kk++) {
        float v = base[(size_t)idx[kk] * 256 + q];
        mx = fmaxf(mx, v - center);
    }
    float* Fp = F + (size_t)b * 512 * 2500;
    Fp[(size_t)(2 * q) * 2500 + t] = center;
    Fp[(size_t)(2 * q + 1) * 2500 + t] = mx;
}

__global__ __launch_bounds__(256)
void out_k(const float* __restrict__ X, float* __restrict__ out)
{
    int idx = blockIdx.x * 256 + threadIdx.x;
    if (idx >= 1280000) return;
    out[idx] = X[idx];
}

// ---------------------------------------------------------------------------
extern "C" void kernel_launch(void* const* d_in, const int* in_sizes, int n_in,
                              void* d_out, int out_size, void* d_ws, size_t ws_size,
                              hipStream_t stream)
{
    (void)in_sizes; (void)n_in; (void)out_size; (void)ws_size;
    const float* x_in = (const float*)d_in[0];
    const float *swp[5], *sbp[5], *sgp[5], *sbep[5];
    for (int i = 0; i < 5; i++) {
        swp[i] = (const float*)d_in[1 + 4 * i];
        sbp[i] = (const float*)d_in[2 + 4 * i];
        sgp[i] = (const float*)d_in[3 + 4 * i];
        sbep[i] = (const float*)d_in[4 + 4 * i];
    }
    const float* fc1_w = (const float*)d_in[21];
    const float* fc1_b = (const float*)d_in[22];
    const float* fc1_g = (const float*)d_in[23];
    const float* fc1_be = (const float*)d_in[24];
    const float* mr_w = (const float*)d_in[25];
    const float* mr_g = (const float*)d_in[26];
    const float* mr_be = (const float*)d_in[27];
    const float* fc2_w = (const float*)d_in[28];
    const float* fc2_b = (const float*)d_in[29];
    const float* fc2_g = (const float*)d_in[30];
    const float* fc2_be = (const float*)d_in[31];
    const float* ffn1_w = (const float*)d_in[32];
    const float* ffn1_b = (const float*)d_in[33];
    const float* ffn1_g = (const float*)d_in[34];
    const float* ffn1_be = (const float*)d_in[35];
    const float* ffn2_w = (const float*)d_in[36];
    const float* ffn2_b = (const float*)d_in[37];
    const float* ffn2_g = (const float*)d_in[38];
    const float* ffn2_be = (const float*)d_in[39];

    float* ws = (float*)d_ws;
    // ---- workspace (fp32 everywhere), total ~72.1 MiB, lifetime-aliased ----
    // A [0 .. 10.24M):    stem ping | HF (1.28M) then NEGc ([2][2048][2500])
    // B [10.24M..15.36M): stem pong | F (2.56M) + G (2.56M); HF2 aliases F
    // C [15.36M..16.64M): X
    // D [16.64M..17.92M): HT
    // tail: SQ(5000) R(5000) STATS(128) IDX(90000 ints)
    const size_t OA = 0, OB = 10240000, OC = 15360000, OD = 16640000;
    const size_t OSQ = 17920000, OR = 17925000, OST = 17930000, OIDX = 17930128;

    float* ping = ws + OA;
    float* pong = ws + OB;
    float* HF   = ws + OA;
    float* NEGc = ws + OA;
    float* F    = ws + OB;              // 2.56M
    float* G    = ws + OB + 2560000;    // 2.56M
    float* HF2  = ws + OB;              // 2.56M (aliases F, dead by then)
    float* X    = ws + OC;
    float* HT   = ws + OD;
    float* SQ   = ws + OSQ;
    float* R    = ws + OR;
    float* STATS = ws + OST;
    int* IDX = (int*)(ws + OIDX);

    // ---------------- stem ----------------
    int Ci[5] = {3, 32, 64, 128, 256}, Co[5] = {32, 64, 128, 256, 256};
    int Hi[5] = {800, 400, 200, 100, 50}, Ho[5] = {400, 200, 100, 50, 50};
    int St[5] = {2, 2, 2, 2, 1};
    int Ssub[5] = {8, 8, 4, 2, 2};
    float* cur = nullptr;
    for (int l = 0; l < 5; l++) {
        float* outb = (l % 2 == 0) ? ping : pong;
        int HWo = Ho[l] * Ho[l];
        dim3 g((HWo + 255) / 256, Co[l] / 16, 2);
        conv3x3_k<<<g, 256, 0, stream>>>((l == 0) ? x_in : cur, swp[l], sbp[l], outb,
                                         Ci[l], Co[l], Hi[l], Hi[l], Ho[l], Ho[l], St[l]);
        zero_k<<<1, 128, 0, stream>>>(STATS);
        int cpg = Co[l] / 32;
        gn_stats_k<<<dim3(Ssub[l], 32, 2), 256, 0, stream>>>(outb, STATS, Co[l], HWo, cpg, Ssub[l]);
        int total = 2 * Co[l] * HWo;
        gn_apply_k<<<(total + 255) / 256, 256, 0, stream>>>(outb, STATS, sgp[l], sbep[l],
                                                            Co[l], HWo, cpg, (l < 4) ? 1 : 0, total);
        cur = outb;
    }
    posadd_k<<<(1280000 + 255) / 256, 256, 0, stream>>>(cur, X);

    // ---------------- 12 Grapher + FFN blocks ----------------
    const int KS[12] = {9, 9, 10, 11, 12, 13, 13, 14, 15, 16, 17, 18};
    const int DILS[12] = {1, 1, 1, 1, 2, 2, 2, 2, 3, 3, 3, 3};
    const int D = 256, N = 2500;
    const int CH = 2048;  // NEG row-chunk: [2][CH][2500] = 10.24M floats = region A

    for (int i = 0; i < 12; i++) {
        // fc1: HF = (W X + b)*g + be  (HF overwrites dead stem-ping region)
        gemm_k<<<dim3(40, 4, 2), 256, 0, stream>>>(
            fc1_w + (size_t)i * D * D, X, HF,
            fc1_b + i * D, fc1_g + i * D, fc1_be + i * D, nullptr, D, N, D, 0);
        // transpose + norms (HF -> HT, R, SQ; HF dead afterwards)
        tok_k<<<20, 256, 0, stream>>>(HF, HT, R, SQ);
        // pairwise distances + top-k, chunked over rows, both batches per dispatch
        for (int r0 = 0; r0 < N; r0 += CH) {
            int rows = (N - r0 < CH) ? (N - r0) : CH;
            dist_k<<<dim3(40, (rows + 63) / 64, 2), 256, 0, stream>>>(HT, R, SQ, NEGc, r0, rows);
            topk_k<<<dim3(rows, 2), 256, 0, stream>>>(NEGc, IDX, r0, rows,
                                                      KS[i] * DILS[i], DILS[i], KS[i]);
        }
        // gather + max-diff + interleaved concat -> F
        gather_k<<<dim3(2500, 2), 256, 0, stream>>>(HT, IDX, F, KS[i]);
        // mr: G = gelu((W F)*g + be), M=512, K=512
        gemm_k<<<dim3(40, 8, 2), 256, 0, stream>>>(
            mr_w + (size_t)i * 512 * 512, F, G,
            nullptr, mr_g + i * 512, mr_be + i * 512, nullptr, 512, N, 512, 1);
        // fc2: X = (W G + b)*g + be + X
        gemm_k<<<dim3(40, 4, 2), 256, 0, stream>>>(
            fc2_w + (size_t)i * D * 512, G, X,
            fc2_b + i * D, fc2_g + i * D, fc2_be + i * D, X, D, N, 512, 0);
        // ffn1: HF2 = gelu((W X + b)*g + be), M=1024 (HF2 aliases dead F)
        gemm_k<<<dim3(40, 16, 2), 256, 0, stream>>>(
            ffn1_w + (size_t)i * 1024 * D, X, HF2,
            ffn1_b + i * 1024, ffn1_g + i * 1024, ffn1_be + i * 1024, nullptr, 1024, N, D, 1);
        // ffn2: X = (W HF2 + b)*g + be + X
        gemm_k<<<dim3(40, 4, 2), 256, 0, stream>>>(
            ffn2_w + (size_t)i * D * 1024, HF2, X,
            ffn2_b + i * D, ffn2_g + i * D, ffn2_be + i * D, X, D, N, 1024, 0);
    }

    out_k<<<(1280000 + 255) / 256, 256, 0, stream>>>(X, (float*)d_out);
}